// Round 1
// baseline (128.602 us; speedup 1.0000x reference)
//
#include <hip/hip_runtime.h>

// Fused attention block: B=4, S=2048, F=512, D=64
//  q = x@Wq + bq ; k = x@Wk + bk ; v = x@Wv + bv      (B,S,D)
//  logits = q@k^T / 8 + (1-mask)*-1e9 ; attn = softmax ; out = attn@v
//
// All GEMMs via v_mfma_f32_16x16x32_bf16 (f32 accumulate).
// Fragment layouts (guide §3, m89/m91-verified):
//   A: lane holds A[row = lane&15][k = (lane>>4)*8 + e], e=0..7
//   B: lane holds B[k = (lane>>4)*8 + e][col = lane&15]
//   C/D: lane holds D[row = (lane>>4)*4 + r][col = lane&15], r=0..3

typedef __attribute__((ext_vector_type(8))) short bhalf8;
typedef __attribute__((ext_vector_type(4))) float fx4;

#define MFMA(a, b, c) __builtin_amdgcn_mfma_f32_16x16x32_bf16((a), (b), (c), 0, 0, 0)

__device__ __forceinline__ short f2bf(float f) {
    union { float f; unsigned u; } v; v.f = f;
    unsigned r = (v.u + 0x7FFFu + ((v.u >> 16) & 1u)) >> 16;  // RNE
    return (short)r;
}

// ---- Kernel 1: W (512x64 f32, row-major [F][D]) -> Wt[3][64][512] bf16 (transposed) ----
__global__ void wt_kernel(const float* __restrict__ Wq,
                          const float* __restrict__ Wk,
                          const float* __restrict__ Wv,
                          short* __restrict__ Wt) {
    int tid = blockIdx.x * blockDim.x + threadIdx.x;   // 0 .. 3*64*512-1
    int m   = tid >> 15;                                // which matrix
    int rem = tid & 32767;
    int d   = rem >> 9;                                 // output col 0..63
    int k   = rem & 511;                                // input feature 0..511
    const float* W = (m == 0) ? Wq : (m == 1) ? Wk : Wv;
    Wt[tid] = f2bf(W[k * 64 + d]);
}

// ---- Kernel 2: QKV projection. 256 thr (4 waves), 64 rows/block, grid 128 ----
// Outputs: Qb,Kb bf16 [B*S][64]; Vt bf16 [B][64][2048]
__global__ void proj_kernel(const float* __restrict__ x,
                            const short* __restrict__ Wt,
                            const float* __restrict__ bq,
                            const float* __restrict__ bk,
                            const float* __restrict__ bv,
                            short* __restrict__ Qb,
                            short* __restrict__ Kb,
                            short* __restrict__ Vt) {
    const int wid  = threadIdx.x >> 6;
    const int lane = threadIdx.x & 63;
    const int g = lane >> 4, c = lane & 15;
    const int rowbase = blockIdx.x * 64 + wid * 16;
    const float* xrow = x + (size_t)(rowbase + c) * 512;   // A row = lane&15

    fx4 acc[12];
#pragma unroll
    for (int t = 0; t < 12; ++t) acc[t] = (fx4){0.f, 0.f, 0.f, 0.f};

#pragma unroll 4
    for (int ks = 0; ks < 16; ++ks) {
        const int k0 = ks * 32 + g * 8;
        const float4 x0 = *(const float4*)(xrow + k0);
        const float4 x1 = *(const float4*)(xrow + k0 + 4);
        bhalf8 a;
        a[0] = f2bf(x0.x); a[1] = f2bf(x0.y); a[2] = f2bf(x0.z); a[3] = f2bf(x0.w);
        a[4] = f2bf(x1.x); a[5] = f2bf(x1.y); a[6] = f2bf(x1.z); a[7] = f2bf(x1.w);
#pragma unroll
        for (int t = 0; t < 12; ++t) {
            const int col = ((t & 3) << 4) + c;
            const bhalf8 bf = *(const bhalf8*)(Wt + (size_t)(((t >> 2) << 6) + col) * 512 + k0);
            acc[t] = MFMA(a, bf, acc[t]);
        }
    }

#pragma unroll
    for (int t = 0; t < 12; ++t) {
        const int mat = t >> 2;
        const int col = ((t & 3) << 4) + c;
        const float bias = (mat == 0 ? bq : mat == 1 ? bk : bv)[col];
#pragma unroll
        for (int r = 0; r < 4; ++r) {
            const int row = rowbase + g * 4 + r;          // D row = (lane>>4)*4+r
            const short hv = f2bf(acc[t][r] + bias);
            if (mat == 0)      Qb[row * 64 + col] = hv;
            else if (mat == 1) Kb[row * 64 + col] = hv;
            else               Vt[((size_t)(row >> 11) * 64 + col) * 2048 + (row & 2047)] = hv;
        }
    }
}

// ---- Kernel 3: flash attention. 1 wave/block, 16 q-rows/wave, grid B*(S/16)=512 ----
__global__ void attn_kernel(const short* __restrict__ Qb,
                            const short* __restrict__ Kb,
                            const short* __restrict__ Vt,
                            const int* __restrict__ mask,
                            float* __restrict__ out) {
    const int lane = threadIdx.x;
    const int g = lane >> 4, c = lane & 15;
    const int b     = blockIdx.x >> 7;
    const int qbase = (blockIdx.x & 127) << 4;
    const short* Qp = Qb + (size_t)(b * 2048 + qbase) * 64;
    const short* Kp = Kb + (size_t)b * 2048 * 64;
    const short* Vp = Vt + (size_t)b * 64 * 2048;
    const int*   mp = mask + b * 2048;

    // Q fragments for the two d-halves (A operand of QK^T)
    const bhalf8 qf0 = *(const bhalf8*)(Qp + c * 64 + g * 8);
    const bhalf8 qf1 = *(const bhalf8*)(Qp + c * 64 + 32 + g * 8);

    float m_r[4], l_r[4];
    fx4 o[4];
#pragma unroll
    for (int r = 0; r < 4; ++r) { m_r[r] = -1e30f; l_r[r] = 0.f; }
#pragma unroll
    for (int dt = 0; dt < 4; ++dt) o[dt] = (fx4){0.f, 0.f, 0.f, 0.f};

    __shared__ short Plds[16][32];

    for (int kt = 0; kt < 64; ++kt) {
        const int kb = kt * 32;
        // ---- QK^T: two 16-key n-tiles, K=64 over two ksteps ----
        fx4 s0 = (fx4){0.f, 0.f, 0.f, 0.f};
        fx4 s1 = (fx4){0.f, 0.f, 0.f, 0.f};
        {
            const short* kp0 = Kp + (size_t)(kb + c) * 64 + g * 8;       // B col = key
            const short* kp1 = Kp + (size_t)(kb + 16 + c) * 64 + g * 8;
            const bhalf8 kf00 = *(const bhalf8*)(kp0);
            const bhalf8 kf01 = *(const bhalf8*)(kp0 + 32);
            const bhalf8 kf10 = *(const bhalf8*)(kp1);
            const bhalf8 kf11 = *(const bhalf8*)(kp1 + 32);
            s0 = MFMA(qf0, kf00, s0); s0 = MFMA(qf1, kf01, s0);
            s1 = MFMA(qf0, kf10, s1); s1 = MFMA(qf1, kf11, s1);
        }
        // ---- mask + scale; online softmax (rows g*4+r, cols = c / c+16) ----
        const float madd0 = mp[kb + c]      ? 0.f : -1e9f;
        const float madd1 = mp[kb + 16 + c] ? 0.f : -1e9f;
        float p0[4], p1[4], tm[4];
#pragma unroll
        for (int r = 0; r < 4; ++r) {
            p0[r] = s0[r] * 0.125f + madd0;
            p1[r] = s1[r] * 0.125f + madd1;
            tm[r] = fmaxf(p0[r], p1[r]);
        }
#pragma unroll
        for (int r = 0; r < 4; ++r) {   // row-max across the 16 lanes of the group
            tm[r] = fmaxf(tm[r], __shfl_xor(tm[r], 1));
            tm[r] = fmaxf(tm[r], __shfl_xor(tm[r], 2));
            tm[r] = fmaxf(tm[r], __shfl_xor(tm[r], 4));
            tm[r] = fmaxf(tm[r], __shfl_xor(tm[r], 8));
        }
        float fac[4];
#pragma unroll
        for (int r = 0; r < 4; ++r) {
            const float nm = fmaxf(m_r[r], tm[r]);
            fac[r] = __expf(m_r[r] - nm);
            m_r[r] = nm;
            p0[r] = __expf(p0[r] - nm);
            p1[r] = __expf(p1[r] - nm);
            float rs = p0[r] + p1[r];
            rs += __shfl_xor(rs, 1);
            rs += __shfl_xor(rs, 2);
            rs += __shfl_xor(rs, 4);
            rs += __shfl_xor(rs, 8);
            l_r[r] = l_r[r] * fac[r] + rs;
        }
#pragma unroll
        for (int dt = 0; dt < 4; ++dt)
#pragma unroll
            for (int r = 0; r < 4; ++r) o[dt][r] *= fac[r];

        // ---- P -> LDS (re-fragment for PV A-operand) ----
#pragma unroll
        for (int r = 0; r < 4; ++r) {
            Plds[g * 4 + r][c]      = f2bf(p0[r]);
            Plds[g * 4 + r][c + 16] = f2bf(p1[r]);
        }
        __syncthreads();
        const bhalf8 pa = *(const bhalf8*)(&Plds[c][g * 8]);   // A row=q, k=key
#pragma unroll
        for (int dt = 0; dt < 4; ++dt) {
            const bhalf8 vf = *(const bhalf8*)(Vp + (size_t)(dt * 16 + c) * 2048 + kb + g * 8);
            o[dt] = MFMA(pa, vf, o[dt]);
        }
        __syncthreads();
    }

    float* op = out + (size_t)(b * 2048 + qbase) * 64;
#pragma unroll
    for (int dt = 0; dt < 4; ++dt)
#pragma unroll
        for (int r = 0; r < 4; ++r)
            op[(g * 4 + r) * 64 + dt * 16 + c] = o[dt][r] / l_r[r];
}

extern "C" void kernel_launch(void* const* d_in, const int* in_sizes, int n_in,
                              void* d_out, int out_size, void* d_ws, size_t ws_size,
                              hipStream_t stream) {
    const float* x    = (const float*)d_in[0];
    const int*   mask = (const int*)d_in[1];
    const float* Wq   = (const float*)d_in[2];
    const float* bq   = (const float*)d_in[3];
    const float* Wk   = (const float*)d_in[4];
    const float* bk   = (const float*)d_in[5];
    const float* Wv   = (const float*)d_in[6];
    const float* bv   = (const float*)d_in[7];
    float* out = (float*)d_out;

    short* Wt = (short*)d_ws;                 // 3*64*512
    short* Qb = Wt + 3 * 64 * 512;            // 4*2048*64
    short* Kb = Qb + 4 * 2048 * 64;           // 4*2048*64
    short* Vt = Kb + 4 * 2048 * 64;           // 4*2048*64  (transposed [B][64][2048])

    wt_kernel<<<384, 256, 0, stream>>>(Wq, Wk, Wv, Wt);
    proj_kernel<<<128, 256, 0, stream>>>(x, Wt, bq, bk, bv, Qb, Kb, Vt);
    attn_kernel<<<512, 64, 0, stream>>>(Qb, Kb, Vt, mask, out);
}

// Round 2
// 65.296 us; speedup vs baseline: 1.9695x; 1.9695x over previous
//
#include <hip/hip_runtime.h>

// Fused attention block: B=4, S=2048, F=512, D=64
//  q = x@Wq + bq ; k = x@Wk + bk ; v = x@Wv + bv      (B,S,D)
//  logits = q@k^T / 8 + (1-mask)*-1e9 ; attn = softmax ; out = attn@v
//
// All GEMMs via v_mfma_f32_16x16x32_bf16 (f32 accumulate).
// Fragment layouts (guide §3, m89/m91-verified):
//   A: lane holds A[row = lane&15][k = (lane>>4)*8 + e], e=0..7
//   B: lane holds B[k = (lane>>4)*8 + e][col = lane&15]
//   C/D: lane holds D[row = (lane>>4)*4 + r][col = lane&15], r=0..3
//
// R2: attn = 8 waves/block, per-wave 256-key split + in-LDS online-softmax
// combine (occupancy 0.5 -> 4 waves/SIMD). proj split by matrix (3x waves).

typedef __attribute__((ext_vector_type(8))) short bhalf8;
typedef __attribute__((ext_vector_type(4))) float fx4;

#define MFMA(a, b, c) __builtin_amdgcn_mfma_f32_16x16x32_bf16((a), (b), (c), 0, 0, 0)

__device__ __forceinline__ short f2bf(float f) {
    union { float f; unsigned u; } v; v.f = f;
    unsigned r = (v.u + 0x7FFFu + ((v.u >> 16) & 1u)) >> 16;  // RNE
    return (short)r;
}

// ---- Kernel 1: W (512x64 f32, row-major [F][D]) -> Wt[3][64][512] bf16 (transposed) ----
__global__ void wt_kernel(const float* __restrict__ Wq,
                          const float* __restrict__ Wk,
                          const float* __restrict__ Wv,
                          short* __restrict__ Wt) {
    int tid = blockIdx.x * blockDim.x + threadIdx.x;   // 0 .. 3*64*512-1
    int m   = tid >> 15;                                // which matrix
    int rem = tid & 32767;
    int d   = rem >> 9;                                 // output col 0..63
    int k   = rem & 511;                                // input feature 0..511
    const float* W = (m == 0) ? Wq : (m == 1) ? Wk : Wv;
    Wt[tid] = f2bf(W[k * 64 + d]);
}

// ---- Kernel 2: QKV projection. 1 wave/block, 16 rows x 1 matrix, grid 512*3 ----
// Outputs: Qb,Kb bf16 [B*S][64]; Vt bf16 [B][64][2048]
__global__ void proj_kernel(const float* __restrict__ x,
                            const short* __restrict__ Wt,
                            const float* __restrict__ bq,
                            const float* __restrict__ bk,
                            const float* __restrict__ bv,
                            short* __restrict__ Qb,
                            short* __restrict__ Kb,
                            short* __restrict__ Vt) {
    const int lane = threadIdx.x;
    const int g = lane >> 4, c = lane & 15;
    const int mat = blockIdx.x % 3;
    const int rt  = blockIdx.x / 3;
    const int rowbase = rt * 16;
    const float* xrow = x + (size_t)(rowbase + c) * 512;      // A row = lane&15
    const short* Wm = Wt + (size_t)mat * 64 * 512;

    fx4 acc[4];
#pragma unroll
    for (int t = 0; t < 4; ++t) acc[t] = (fx4){0.f, 0.f, 0.f, 0.f};

#pragma unroll 4
    for (int ks = 0; ks < 16; ++ks) {
        const int k0 = ks * 32 + g * 8;
        const float4 x0 = *(const float4*)(xrow + k0);
        const float4 x1 = *(const float4*)(xrow + k0 + 4);
        bhalf8 a;
        a[0] = f2bf(x0.x); a[1] = f2bf(x0.y); a[2] = f2bf(x0.z); a[3] = f2bf(x0.w);
        a[4] = f2bf(x1.x); a[5] = f2bf(x1.y); a[6] = f2bf(x1.z); a[7] = f2bf(x1.w);
#pragma unroll
        for (int t = 0; t < 4; ++t) {
            const bhalf8 bf = *(const bhalf8*)(Wm + (size_t)(t * 16 + c) * 512 + k0);
            acc[t] = MFMA(a, bf, acc[t]);
        }
    }

    const float* bias = (mat == 0) ? bq : (mat == 1) ? bk : bv;
#pragma unroll
    for (int t = 0; t < 4; ++t) {
        const int col = t * 16 + c;
        const float bv_ = bias[col];
#pragma unroll
        for (int r = 0; r < 4; ++r) {
            const int row = rowbase + g * 4 + r;          // D row = (lane>>4)*4+r
            const short hv = f2bf(acc[t][r] + bv_);
            if (mat == 0)      Qb[row * 64 + col] = hv;
            else if (mat == 1) Kb[row * 64 + col] = hv;
            else               Vt[((size_t)(row >> 11) * 64 + col) * 2048 + (row & 2047)] = hv;
        }
    }
}

// ---- Kernel 3: flash attention. 8 waves/block, 16 q-rows/block, per-wave
// 256-key slice with private online softmax, LDS combine. grid B*(S/16)=512 ----
__global__ __launch_bounds__(512) void attn_kernel(const short* __restrict__ Qb,
                                                   const short* __restrict__ Kb,
                                                   const short* __restrict__ Vt,
                                                   const int* __restrict__ mask,
                                                   float* __restrict__ out) {
    const int tid  = threadIdx.x;
    const int wid  = tid >> 6;
    const int lane = tid & 63;
    const int g = lane >> 4, c = lane & 15;
    const int b     = blockIdx.x >> 7;
    const int qbase = (blockIdx.x & 127) << 4;
    const short* Qp = Qb + (size_t)(b * 2048 + qbase) * 64;
    const short* Kp = Kb + (size_t)b * 2048 * 64;
    const short* Vp = Vt + (size_t)b * 64 * 2048;
    const int*   mp = mask + b * 2048;

    // Q fragments for the two d-halves (A operand of QK^T)
    const bhalf8 qf0 = *(const bhalf8*)(Qp + c * 64 + g * 8);
    const bhalf8 qf1 = *(const bhalf8*)(Qp + c * 64 + 32 + g * 8);

    float m_r[4], l_r[4];
    fx4 o[4];
#pragma unroll
    for (int r = 0; r < 4; ++r) { m_r[r] = -1e30f; l_r[r] = 0.f; }
#pragma unroll
    for (int dt = 0; dt < 4; ++dt) o[dt] = (fx4){0.f, 0.f, 0.f, 0.f};

    __shared__ float olds[8][16][65];   // per-wave partial O (pad 65: no bank clash)
    __shared__ float mlds[8][16];
    __shared__ float llds[8][16];
    __shared__ short Plds[8][16][40];   // pad 40: 16B-aligned rows, even bank spread

    for (int kt = 0; kt < 8; ++kt) {
        const int kb = (wid * 8 + kt) * 32;
        // ---- QK^T: two 16-key n-tiles, K=64 over two ksteps ----
        fx4 s0 = (fx4){0.f, 0.f, 0.f, 0.f};
        fx4 s1 = (fx4){0.f, 0.f, 0.f, 0.f};
        {
            const short* kp0 = Kp + (size_t)(kb + c) * 64 + g * 8;       // B col = key
            const short* kp1 = Kp + (size_t)(kb + 16 + c) * 64 + g * 8;
            const bhalf8 kf00 = *(const bhalf8*)(kp0);
            const bhalf8 kf01 = *(const bhalf8*)(kp0 + 32);
            const bhalf8 kf10 = *(const bhalf8*)(kp1);
            const bhalf8 kf11 = *(const bhalf8*)(kp1 + 32);
            s0 = MFMA(qf0, kf00, s0); s0 = MFMA(qf1, kf01, s0);
            s1 = MFMA(qf0, kf10, s1); s1 = MFMA(qf1, kf11, s1);
        }
        // ---- mask + scale; online softmax (rows g*4+r, cols = c / c+16) ----
        const float madd0 = mp[kb + c]      ? 0.f : -1e9f;
        const float madd1 = mp[kb + 16 + c] ? 0.f : -1e9f;
        float p0[4], p1[4], tm[4];
#pragma unroll
        for (int r = 0; r < 4; ++r) {
            p0[r] = s0[r] * 0.125f + madd0;
            p1[r] = s1[r] * 0.125f + madd1;
            tm[r] = fmaxf(p0[r], p1[r]);
        }
#pragma unroll
        for (int r = 0; r < 4; ++r) {   // row-max across the 16 lanes of the group
            tm[r] = fmaxf(tm[r], __shfl_xor(tm[r], 1));
            tm[r] = fmaxf(tm[r], __shfl_xor(tm[r], 2));
            tm[r] = fmaxf(tm[r], __shfl_xor(tm[r], 4));
            tm[r] = fmaxf(tm[r], __shfl_xor(tm[r], 8));
        }
        float fac[4];
#pragma unroll
        for (int r = 0; r < 4; ++r) {
            const float nm = fmaxf(m_r[r], tm[r]);
            fac[r] = __expf(m_r[r] - nm);
            m_r[r] = nm;
            p0[r] = __expf(p0[r] - nm);
            p1[r] = __expf(p1[r] - nm);
            float rs = p0[r] + p1[r];
            rs += __shfl_xor(rs, 1);
            rs += __shfl_xor(rs, 2);
            rs += __shfl_xor(rs, 4);
            rs += __shfl_xor(rs, 8);
            l_r[r] = l_r[r] * fac[r] + rs;
        }
#pragma unroll
        for (int dt = 0; dt < 4; ++dt)
#pragma unroll
            for (int r = 0; r < 4; ++r) o[dt][r] *= fac[r];

        // ---- P -> LDS (re-fragment for PV A-operand); intra-wave only ----
        asm volatile("" ::: "memory");
#pragma unroll
        for (int r = 0; r < 4; ++r) {
            Plds[wid][g * 4 + r][c]      = f2bf(p0[r]);
            Plds[wid][g * 4 + r][c + 16] = f2bf(p1[r]);
        }
        asm volatile("s_waitcnt lgkmcnt(0)" ::: "memory");
        const bhalf8 pa = *(const bhalf8*)(&Plds[wid][c][g * 8]);  // A row=q, k=key
#pragma unroll
        for (int dt = 0; dt < 4; ++dt) {
            const bhalf8 vf = *(const bhalf8*)(Vp + (size_t)(dt * 16 + c) * 2048 + kb + g * 8);
            o[dt] = MFMA(pa, vf, o[dt]);
        }
    }

    // ---- publish per-wave partial state ----
    if (c == 0) {
#pragma unroll
        for (int r = 0; r < 4; ++r) {
            mlds[wid][g * 4 + r] = m_r[r];
            llds[wid][g * 4 + r] = l_r[r];
        }
    }
#pragma unroll
    for (int dt = 0; dt < 4; ++dt)
#pragma unroll
        for (int r = 0; r < 4; ++r)
            olds[wid][g * 4 + r][dt * 16 + c] = o[dt][r];
    __syncthreads();

    // ---- cross-wave combine: out = sum_w e^{m_w-M} o_w / sum_w e^{m_w-M} l_w ----
    float* op = out + (size_t)(b * 2048 + qbase) * 64;
#pragma unroll
    for (int i = 0; i < 2; ++i) {
        const int idx = tid + i * 512;        // 0..1023 over (row,d)
        const int row = idx >> 6, d = idx & 63;
        float M = mlds[0][row];
#pragma unroll
        for (int w = 1; w < 8; ++w) M = fmaxf(M, mlds[w][row]);
        float num = 0.f, den = 0.f;
#pragma unroll
        for (int w = 0; w < 8; ++w) {
            const float wt = __expf(mlds[w][row] - M);
            num += wt * olds[w][row][d];
            den += wt * llds[w][row];
        }
        op[row * 64 + d] = num / den;
    }
}

extern "C" void kernel_launch(void* const* d_in, const int* in_sizes, int n_in,
                              void* d_out, int out_size, void* d_ws, size_t ws_size,
                              hipStream_t stream) {
    const float* x    = (const float*)d_in[0];
    const int*   mask = (const int*)d_in[1];
    const float* Wq   = (const float*)d_in[2];
    const float* bq   = (const float*)d_in[3];
    const float* Wk   = (const float*)d_in[4];
    const float* bk   = (const float*)d_in[5];
    const float* Wv   = (const float*)d_in[6];
    const float* bv   = (const float*)d_in[7];
    float* out = (float*)d_out;

    short* Wt = (short*)d_ws;                 // 3*64*512
    short* Qb = Wt + 3 * 64 * 512;            // 4*2048*64
    short* Kb = Qb + 4 * 2048 * 64;           // 4*2048*64
    short* Vt = Kb + 4 * 2048 * 64;           // 4*2048*64  (transposed [B][64][2048])

    wt_kernel<<<384, 256, 0, stream>>>(Wq, Wk, Wv, Wt);
    proj_kernel<<<1536, 64, 0, stream>>>(x, Wt, bq, bk, bv, Qb, Kb, Vt);
    attn_kernel<<<512, 512, 0, stream>>>(Qb, Kb, Vt, mask, out);
}